// Round 9
// baseline (373.932 us; speedup 1.0000x reference)
//
#include <hip/hip_runtime.h>

#define B_  16
#define C_  512
#define N_  1024
#define NH  4
#define DK  128
#define M3  1536   // 3*C

typedef unsigned short u16;
typedef unsigned int   u32;
typedef __attribute__((ext_vector_type(8))) short bfrag;   // 8 bf16 (4 VGPR)
typedef __attribute__((ext_vector_type(4))) float f4;      // MFMA C/D

#define MFMA(a, b, c) __builtin_amdgcn_mfma_f32_16x16x32_bf16(a, b, c, 0, 0, 0)

// async global->LDS, 16B per lane, lane l lands at lds_base + l*16
#define GL2LDS(gp, lp) __builtin_amdgcn_global_load_lds( \
    (__attribute__((address_space(1))) const unsigned int*)(const void*)(gp), \
    (__attribute__((address_space(3))) unsigned int*)(void*)(lp), 16, 0, 0)

__device__ __forceinline__ u16 f2bf(float f) {            // RNE fp32->bf16 (no NaN inputs)
    u32 u = __float_as_uint(f);
    return (u16)((u + 0x7FFFu + ((u >> 16) & 1u)) >> 16);
}
__device__ __forceinline__ float bf2f(u16 h) { return __uint_as_float(((u32)h) << 16); }

// dk^-0.5 * log2(e): folded into stored Q so attn uses exp2 directly
#define QSCL 0.12751741859316937f

// ---------------------------------------------------------------------------
// Convert: src fp32 [R][Cc] (batched via z) -> dst_hi/lo bf16 [Cc][R] (transpose+split)
// ---------------------------------------------------------------------------
__global__ __launch_bounds__(256) void conv_split_t(
    const float* __restrict__ src, u16* __restrict__ dhi, u16* __restrict__ dlo,
    int R, int Cc)
{
    __shared__ float Ts[64][65];
    const int tid = threadIdx.x;
    const int c0 = blockIdx.x * 64, r0 = blockIdx.y * 64;
    const size_t bofs = (size_t)blockIdx.z * R * Cc;

#pragma unroll
    for (int p = 0; p < 4; ++p) {
        int r = p * 16 + (tid >> 4);
        int c = (tid & 15) * 4;
        float4 v = *(const float4*)(src + bofs + (size_t)(r0 + r) * Cc + c0 + c);
        Ts[c + 0][r] = v.x; Ts[c + 1][r] = v.y; Ts[c + 2][r] = v.z; Ts[c + 3][r] = v.w;
    }
    __syncthreads();
#pragma unroll
    for (int p = 0; p < 4; ++p) {
        int cc = p * 16 + (tid >> 4);
        int rr = (tid & 15) * 4;
        float f0 = Ts[cc][rr + 0], f1 = Ts[cc][rr + 1];
        float f2 = Ts[cc][rr + 2], f3 = Ts[cc][rr + 3];
        u16 h0 = f2bf(f0), h1 = f2bf(f1), h2 = f2bf(f2), h3 = f2bf(f3);
        u16 l0 = f2bf(f0 - bf2f(h0)), l1 = f2bf(f1 - bf2f(h1));
        u16 l2 = f2bf(f2 - bf2f(h2)), l3 = f2bf(f3 - bf2f(h3));
        size_t o = bofs + (size_t)(c0 + cc) * R + r0 + rr;
        *(uint2*)(void*)(dhi + o) = make_uint2((u32)h0 | ((u32)h1 << 16), (u32)h2 | ((u32)h3 << 16));
        *(uint2*)(void*)(dlo + o) = make_uint2((u32)l0 | ((u32)l1 << 16), (u32)l2 | ((u32)l3 << 16));
    }
}

// ---------------------------------------------------------------------------
// QKV projection, split-bf16 MFMA. Epilogue: LDS bounce (128x129 f32) then
// COALESCED uint4 stores (fixes round-8's 128x scattered 2B stores/lane).
//   Q hi/lo [b][h][n][d] (prescaled), K hi/lo [b][h][n][d], Vt hi/lo [b][h][d][n]
// ---------------------------------------------------------------------------
__global__ __launch_bounds__(256, 2) void qkv_mfma(
    const u16* __restrict__ xt_hi, const u16* __restrict__ xt_lo,
    const u16* __restrict__ wpT_hi, const u16* __restrict__ wpT_lo,
    const float* __restrict__ bp,
    u16* __restrict__ Qh, u16* __restrict__ Ql,
    u16* __restrict__ Kh, u16* __restrict__ Kl,
    u16* __restrict__ Vth, u16* __restrict__ Vtl)
{
    __shared__ __align__(16) u32 SMEM[16512];   // 66,048 B: staging (64K) | bounce 128x129 f32
    u16* AH = (u16*)SMEM;
    u16* AL = AH + 128 * 64;
    u16* BH = AL + 128 * 64;
    u16* BL = BH + 128 * 64;
    float* FB = (float*)SMEM;

    const int tid = threadIdx.x;
    const int l = tid & 63, w = tid >> 6;
    const int wr = w >> 1, wc = w & 1;
    const int lm = l & 15, kg = l >> 4;
    const int bx = blockIdx.x, by = blockIdx.y, b = blockIdx.z;
    const int m0 = bx * 128, n0 = by * 128;

    const u16* gsrc =
        (w == 0) ? xt_hi + ((size_t)b * N_ + n0) * C_ :
        (w == 1) ? xt_lo + ((size_t)b * N_ + n0) * C_ :
        (w == 2) ? wpT_hi + (size_t)m0 * C_ :
                   wpT_lo + (size_t)m0 * C_;
    u16* ldst = (w == 0) ? AH : (w == 1) ? AL : (w == 2) ? BH : BL;
    const int lane_off = (l >> 3) * C_ + (((l & 7) ^ (l >> 3)) << 3);

    f4 acc[4][4] = {};

    for (int it = 0; it < 8; ++it) {
        __syncthreads();
        const u16* g = gsrc + it * 64 + lane_off;
#pragma unroll
        for (int u = 0; u < 16; ++u)
            GL2LDS(g + (size_t)u * 8 * C_, ldst + u * 512);
        __syncthreads();

#pragma unroll
        for (int kk = 0; kk < 2; ++kk) {
            bfrag ah[4], al[4], bh[4], bl[4];
            const int s = ((kk * 4 + kg) ^ (lm & 7)) << 3;
#pragma unroll
            for (int f = 0; f < 4; ++f) {
                const int ar = wr * 64 + f * 16 + lm;
                const int br = wc * 64 + f * 16 + lm;
                ah[f] = *(const bfrag*)(AH + ar * 64 + s);
                al[f] = *(const bfrag*)(AL + ar * 64 + s);
                bh[f] = *(const bfrag*)(BH + br * 64 + s);
                bl[f] = *(const bfrag*)(BL + br * 64 + s);
            }
#pragma unroll
            for (int i = 0; i < 4; ++i)
#pragma unroll
                for (int j = 0; j < 4; ++j) {
                    acc[i][j] = MFMA(ah[i], bh[j], acc[i][j]);
                    acc[i][j] = MFMA(ah[i], bl[j], acc[i][j]);
                    acc[i][j] = MFMA(al[i], bh[j], acc[i][j]);
                }
        }
    }

    // ---- epilogue: bounce through LDS, then coalesced split stores ----
    const int hh = bx / 3, t = bx - hh * 3;
    __syncthreads();   // staging reads done; FB may overwrite
    {
        float bias_j[4];
#pragma unroll
        for (int j = 0; j < 4; ++j) bias_j[j] = bp[m0 + wc * 64 + j * 16 + lm];
#pragma unroll
        for (int j = 0; j < 4; ++j) {
            const int col = wc * 64 + j * 16 + lm;     // m-dim (d)
#pragma unroll
            for (int i = 0; i < 4; ++i) {
#pragma unroll
                for (int r = 0; r < 4; ++r) {
                    const int tok = wr * 64 + i * 16 + kg * 4 + r;
                    float v = acc[i][j][r] + bias_j[j];
                    if (t == 0) v *= QSCL;
                    if (t == 2) FB[col * 129 + tok] = v;   // V: [d][token]
                    else        FB[tok * 129 + col] = v;   // Q/K: [token][d]
                }
            }
        }
    }
    __syncthreads();
    {
        const int r2 = tid >> 1, h = tid & 1;
        const float* src = FB + r2 * 129 + h * 64;
        u16* dsth; u16* dstl; size_t o;
        if (t == 2) {
            dsth = Vth; dstl = Vtl;
            o = ((size_t)(b * NH + hh) * DK + r2) * N_ + n0 + h * 64;
        } else {
            dsth = (t == 0) ? Qh : Kh;
            dstl = (t == 0) ? Ql : Kl;
            o = ((size_t)(b * NH + hh) * N_ + n0 + r2) * DK + h * 64;
        }
#pragma unroll
        for (int c0 = 0; c0 < 64; c0 += 8) {
            u16 hb[8], lb[8];
#pragma unroll
            for (int c = 0; c < 8; ++c) {
                float v = src[c0 + c];
                hb[c] = f2bf(v);
                lb[c] = f2bf(v - bf2f(hb[c]));
            }
            *(uint4*)(void*)(dsth + o + c0) = make_uint4(
                (u32)hb[0] | ((u32)hb[1] << 16), (u32)hb[2] | ((u32)hb[3] << 16),
                (u32)hb[4] | ((u32)hb[5] << 16), (u32)hb[6] | ((u32)hb[7] << 16));
            *(uint4*)(void*)(dstl + o + c0) = make_uint4(
                (u32)lb[0] | ((u32)lb[1] << 16), (u32)lb[2] | ((u32)lb[3] << 16),
                (u32)lb[4] | ((u32)lb[5] << 16), (u32)lb[6] | ((u32)lb[7] << 16));
        }
    }
}

// ---------------------------------------------------------------------------
// Flash attention, split-bf16 MFMA, swapped operands (S^T = K·Q^T).
// 256 threads = 4 waves, 2 q-sets/wave (128 rows/block), KVBLK=32.
// LDS 53 KB -> grid (64,8) = 512 blocks = 2 blocks/CU: two independent
// barrier groups per CU so staging drains + softmax of one block overlap
// MFMA of the other (round-8 was 1 block/CU and serialization-bound at
// MfmaUtil 31%). Softmax shfl chains ILP-fused across the 2 sets.
// ---------------------------------------------------------------------------
__global__ __launch_bounds__(256, 2) void attn_mfma(
    const u16* __restrict__ Qh_, const u16* __restrict__ Ql_,
    const u16* __restrict__ Kh_, const u16* __restrict__ Kl_,
    const u16* __restrict__ Vth_, const u16* __restrict__ Vtl_,
    u16* __restrict__ res_hi, u16* __restrict__ res_lo)
{
    __shared__ __align__(16) u16 KH[32 * 128], KL[32 * 128];   // [j][d], chunk-swizzled
    __shared__ __align__(16) u16 VH[128 * 32], VL[128 * 32];   // [d][n], chunk-swizzled
    __shared__ u16 Ph[4][2][16][40], Pl[4][2][16][40];         // per-wave, per-set

    const int tid = threadIdx.x;
    const int l = tid & 63, w = tid >> 6;     // 4 waves
    const int lm = l & 15, kg = l >> 4;
    const int bh = blockIdx.x;                // 0..63 (b*NH+h)
    const int qc = blockIdx.y;                // 0..7
    const int i0s = qc * 128 + w * 16 + lm;   // set0 q-row; set1 = +64
    const size_t head = (size_t)bh * N_ * DK;

    // Q fragments (B-operand), both sets
    bfrag qfh[2][4], qfl[2][4];
#pragma unroll
    for (int s = 0; s < 2; ++s) {
        const u16* qp  = Qh_ + head + (size_t)(i0s + s * 64) * DK + kg * 8;
        const u16* qp2 = Ql_ + head + (size_t)(i0s + s * 64) * DK + kg * 8;
#pragma unroll
        for (int kc = 0; kc < 4; ++kc) {
            qfh[s][kc] = *(const bfrag*)(qp + kc * 32);
            qfl[s][kc] = *(const bfrag*)(qp2 + kc * 32);
        }
    }

    f4 acc_o[2][8] = {};
    float m_r[2] = {-3.0e38f, -3.0e38f}, l_r[2] = {0.f, 0.f};

    for (int jt = 0; jt < 32; ++jt) {
        __syncthreads();   // prior iteration's K/V LDS reads complete
        if (w < 2) {
            const u16* sg = (w & 1) ? Kl_ : Kh_;
            u16* sd = (w & 1) ? KL : KH;
#pragma unroll
            for (int u = 0; u < 8; ++u) {
                const int rbase = u * 4;
                const int row = rbase + (l >> 4);
                GL2LDS(sg + head + (size_t)(jt * 32 + row) * DK + (((l & 15) ^ (row & 7)) << 3),
                       sd + rbase * 128);
            }
        } else {
            const u16* sg = (w & 1) ? Vtl_ : Vth_;
            u16* sd = (w & 1) ? VL : VH;
#pragma unroll
            for (int u = 0; u < 8; ++u) {
                const int rbase = u * 16;
                const int row = rbase + (l >> 2);
                GL2LDS(sg + (size_t)bh * DK * N_ + (size_t)row * N_ + jt * 32
                           + (((l & 3) ^ (row & 3)) << 3),
                       sd + rbase * 32);
            }
        }
        __syncthreads();   // staging landed (vmcnt(0) drained at barrier)

        // ---- S^T = K·Q^T over d=128, both q-sets share each K fragment ----
        f4 sacc[2][2] = {};
#pragma unroll
        for (int kc = 0; kc < 4; ++kc) {
#pragma unroll
            for (int jf = 0; jf < 2; ++jf) {
                const int row = jf * 16 + lm;
                const int sw = (((kc << 2) | kg) ^ (lm & 7)) << 3;
                bfrag kh = *(const bfrag*)(KH + row * 128 + sw);
                bfrag kl = *(const bfrag*)(KL + row * 128 + sw);
#pragma unroll
                for (int s = 0; s < 2; ++s) {
                    sacc[s][jf] = MFMA(kh, qfh[s][kc], sacc[s][jf]);
                    sacc[s][jf] = MFMA(kh, qfl[s][kc], sacc[s][jf]);
                    sacc[s][jf] = MFMA(kl, qfh[s][kc], sacc[s][jf]);
                }
            }
        }

        // ---- online softmax; shfl chains ILP-fused across sets ----
        float mt[2], mn[2], alpha[2], rs[2];
#pragma unroll
        for (int s = 0; s < 2; ++s) {
            float a = fmaxf(fmaxf(sacc[s][0][0], sacc[s][0][1]),
                            fmaxf(sacc[s][0][2], sacc[s][0][3]));
            float bb = fmaxf(fmaxf(sacc[s][1][0], sacc[s][1][1]),
                             fmaxf(sacc[s][1][2], sacc[s][1][3]));
            mt[s] = fmaxf(a, bb);
        }
        mt[0] = fmaxf(mt[0], __shfl_xor(mt[0], 16));
        mt[1] = fmaxf(mt[1], __shfl_xor(mt[1], 16));
        mt[0] = fmaxf(mt[0], __shfl_xor(mt[0], 32));
        mt[1] = fmaxf(mt[1], __shfl_xor(mt[1], 32));
#pragma unroll
        for (int s = 0; s < 2; ++s) {
            mn[s] = fmaxf(m_r[s], mt[s]);
            alpha[s] = exp2f(m_r[s] - mn[s]);
            m_r[s] = mn[s];
            rs[s] = 0.f;
#pragma unroll
            for (int jf = 0; jf < 2; ++jf) {
                u16 hb[4], lb[4];
#pragma unroll
                for (int r = 0; r < 4; ++r) {
                    float pv = exp2f(sacc[s][jf][r] - mn[s]);
                    rs[s] += pv;
                    hb[r] = f2bf(pv);
                    lb[r] = f2bf(pv - bf2f(hb[r]));
                }
                *(uint2*)(void*)&Ph[w][s][lm][jf * 16 + kg * 4] =
                    make_uint2((u32)hb[0] | ((u32)hb[1] << 16), (u32)hb[2] | ((u32)hb[3] << 16));
                *(uint2*)(void*)&Pl[w][s][lm][jf * 16 + kg * 4] =
                    make_uint2((u32)lb[0] | ((u32)lb[1] << 16), (u32)lb[2] | ((u32)lb[3] << 16));
            }
        }
        rs[0] += __shfl_xor(rs[0], 16);
        rs[1] += __shfl_xor(rs[1], 16);
        rs[0] += __shfl_xor(rs[0], 32);
        rs[1] += __shfl_xor(rs[1], 32);
#pragma unroll
        for (int s = 0; s < 2; ++s) {
            l_r[s] = l_r[s] * alpha[s] + rs[s];
#pragma unroll
            for (int df = 0; df < 8; ++df)
#pragma unroll
                for (int r = 0; r < 4; ++r) acc_o[s][df][r] *= alpha[s];
        }

        // ---- O^T += Vt · P, both P-sets share each V fragment ----
        bfrag pbh0 = *(const bfrag*)&Ph[w][0][lm][kg * 8];
        bfrag pbl0 = *(const bfrag*)&Pl[w][0][lm][kg * 8];
        bfrag pbh1 = *(const bfrag*)&Ph[w][1][lm][kg * 8];
        bfrag pbl1 = *(const bfrag*)&Pl[w][1][lm][kg * 8];
#pragma unroll
        for (int df = 0; df < 8; ++df) {
            const int row = df * 16 + lm;
            const int sw = (kg ^ (lm & 3)) << 3;
            bfrag vh = *(const bfrag*)(VH + row * 32 + sw);
            bfrag vl = *(const bfrag*)(VL + row * 32 + sw);
            acc_o[0][df] = MFMA(vh, pbh0, acc_o[0][df]);
            acc_o[0][df] = MFMA(vh, pbl0, acc_o[0][df]);
            acc_o[0][df] = MFMA(vl, pbh0, acc_o[0][df]);
            acc_o[1][df] = MFMA(vh, pbh1, acc_o[1][df]);
            acc_o[1][df] = MFMA(vh, pbl1, acc_o[1][df]);
            acc_o[1][df] = MFMA(vl, pbh1, acc_o[1][df]);
        }
    }

    // ---- epilogue: res[b][i][h*128+d] = O/l as bf16 hi/lo, both sets ----
    const int b = bh >> 2, h = bh & 3;
#pragma unroll
    for (int s = 0; s < 2; ++s) {
        const float inv = 1.f / l_r[s];
        const size_t ro = ((size_t)b * N_ + i0s + s * 64) * C_ + h * DK;
#pragma unroll
        for (int df = 0; df < 8; ++df) {
            u16 hb[4], lb[4];
#pragma unroll
            for (int r = 0; r < 4; ++r) {
                float v = acc_o[s][df][r] * inv;
                hb[r] = f2bf(v);
                lb[r] = f2bf(v - bf2f(hb[r]));
            }
            const size_t o = ro + df * 16 + kg * 4;
            *(uint2*)(void*)(res_hi + o) = make_uint2((u32)hb[0] | ((u32)hb[1] << 16),
                                                      (u32)hb[2] | ((u32)hb[3] << 16));
            *(uint2*)(void*)(res_lo + o) = make_uint2((u32)lb[0] | ((u32)lb[1] << 16),
                                                      (u32)lb[2] | ((u32)lb[3] << 16));
        }
    }
}

// ---------------------------------------------------------------------------
// Out projection, split-bf16 MFMA, computes outT[c'][n] directly. (+bias +x)
// ---------------------------------------------------------------------------
__global__ __launch_bounds__(256, 2) void out_mfma(
    const u16* __restrict__ woT_hi, const u16* __restrict__ woT_lo,
    const u16* __restrict__ res_hi, const u16* __restrict__ res_lo,
    const float* __restrict__ bo, const float* __restrict__ x,
    float* __restrict__ out)
{
    __shared__ __align__(16) u16 AH[128 * 64], AL[128 * 64], BH[128 * 64], BL[128 * 64];
    const int tid = threadIdx.x;
    const int l = tid & 63, w = tid >> 6;
    const int wr = w >> 1, wc = w & 1;
    const int lm = l & 15, kg = l >> 4;
    const int bx = blockIdx.x, by = blockIdx.y, b = blockIdx.z;
    const int c0 = bx * 128, n0 = by * 128;

    const u16* gsrc =
        (w == 0) ? woT_hi + (size_t)c0 * C_ :
        (w == 1) ? woT_lo + (size_t)c0 * C_ :
        (w == 2) ? res_hi + ((size_t)b * N_ + n0) * C_ :
                   res_lo + ((size_t)b * N_ + n0) * C_;
    u16* ldst = (w == 0) ? AH : (w == 1) ? AL : (w == 2) ? BH : BL;
    const int lane_off = (l >> 3) * C_ + (((l & 7) ^ (l >> 3)) << 3);

    f4 acc[4][4] = {};

    for (int it = 0; it < 8; ++it) {
        __syncthreads();
        const u16* g = gsrc + it * 64 + lane_off;
#pragma unroll
        for (int u = 0; u < 16; ++u)
            GL2LDS(g + (size_t)u * 8 * C_, ldst + u * 512);
        __syncthreads();

#pragma unroll
        for (int kk = 0; kk < 2; ++kk) {
            bfrag ah[4], al[4], bh[4], bl[4];
            const int s = ((kk * 4 + kg) ^ (lm & 7)) << 3;
#pragma unroll
            for (int f = 0; f < 4; ++f) {
                const int ar = wr * 64 + f * 16 + lm;
                const int br = wc * 64 + f * 16 + lm;
                ah[f] = *(const bfrag*)(AH + ar * 64 + s);
                al[f] = *(const bfrag*)(AL + ar * 64 + s);
                bh[f] = *(const bfrag*)(BH + br * 64 + s);
                bl[f] = *(const bfrag*)(BL + br * 64 + s);
            }
#pragma unroll
            for (int i = 0; i < 4; ++i)
#pragma unroll
                for (int j = 0; j < 4; ++j) {
                    acc[i][j] = MFMA(ah[i], bh[j], acc[i][j]);
                    acc[i][j] = MFMA(ah[i], bl[j], acc[i][j]);
                    acc[i][j] = MFMA(al[i], bh[j], acc[i][j]);
                }
        }
    }

#pragma unroll
    for (int j = 0; j < 4; ++j) {
        const int ncol = n0 + wc * 64 + j * 16 + lm;
#pragma unroll
        for (int i = 0; i < 4; ++i) {
#pragma unroll
            for (int r = 0; r < 4; ++r) {
                const int crow = c0 + wr * 64 + i * 16 + kg * 4 + r;
                const size_t o = ((size_t)b * C_ + crow) * N_ + ncol;
                out[o] = acc[i][j][r] + bo[crow] + x[o];
            }
        }
    }
}

extern "C" void kernel_launch(void* const* d_in, const int* in_sizes, int n_in,
                              void* d_out, int out_size, void* d_ws, size_t ws_size,
                              hipStream_t stream) {
    const float* x  = (const float*)d_in[0];
    const float* wp = (const float*)d_in[1];
    const float* bp = (const float*)d_in[2];
    const float* wo = (const float*)d_in[3];
    const float* bo = (const float*)d_in[4];
    float* out = (float*)d_out;

    // ws map (128 MiB). SEG = 8388608 elements.
    //  [0,32M):   xt hi/lo  -> res hi/lo after qkv
    //  [32M,64M): Q hi/lo   (-> woT hi/lo after attn)
    //  [64M,96M): K hi/lo
    //  [96M,128M): Vt hi/lo
    // d_out[0,3M): wpT hi/lo (dead before out_mfma overwrites with output)
    const size_t SEG = (size_t)B_ * N_ * C_;
    u16* xt_hi = (u16*)d_ws;
    u16* xt_lo = xt_hi + SEG;
    u16* Qh  = xt_hi + 2 * SEG;
    u16* Ql  = Qh + SEG;
    u16* Kh  = Ql + SEG;
    u16* Kl  = Kh + SEG;
    u16* Vth = Kl + SEG;
    u16* Vtl = Vth + SEG;
    u16* res_hi = xt_hi;
    u16* res_lo = xt_lo;
    u16* woT_hi = Qh;
    u16* woT_lo = woT_hi + C_ * C_;
    u16* wpT_hi = (u16*)d_out;
    u16* wpT_lo = wpT_hi + C_ * M3;

    conv_split_t<<<dim3(16, 8, 16), 256, 0, stream>>>(x, xt_hi, xt_lo, C_, N_);
    conv_split_t<<<dim3(24, 8, 1), 256, 0, stream>>>(wp, wpT_hi, wpT_lo, C_, M3);
    qkv_mfma<<<dim3(12, 8, 16), 256, 0, stream>>>(xt_hi, xt_lo, wpT_hi, wpT_lo, bp,
                                                  Qh, Ql, Kh, Kl, Vth, Vtl);
    attn_mfma<<<dim3(64, 8), 256, 0, stream>>>(Qh, Ql, Kh, Kl, Vth, Vtl, res_hi, res_lo);
    conv_split_t<<<dim3(8, 8, 1), 256, 0, stream>>>(wo, woT_hi, woT_lo, C_, C_);
    out_mfma<<<dim3(4, 8, 16), 256, 0, stream>>>(woT_hi, woT_lo, res_hi, res_lo, bo, x, out);
}

// Round 10
// 341.024 us; speedup vs baseline: 1.0965x; 1.0965x over previous
//
#include <hip/hip_runtime.h>

#define B_  16
#define C_  512
#define N_  1024
#define NH  4
#define DK  128
#define M3  1536   // 3*C

typedef unsigned short u16;
typedef unsigned int   u32;
typedef __attribute__((ext_vector_type(8))) short bfrag;   // 8 bf16 (4 VGPR)
typedef __attribute__((ext_vector_type(4))) float f4;      // MFMA C/D

#define MFMA(a, b, c) __builtin_amdgcn_mfma_f32_16x16x32_bf16(a, b, c, 0, 0, 0)

// async global->LDS, 16B per lane, lane l lands at lds_base + l*16
#define GL2LDS(gp, lp) __builtin_amdgcn_global_load_lds( \
    (__attribute__((address_space(1))) const unsigned int*)(const void*)(gp), \
    (__attribute__((address_space(3))) unsigned int*)(void*)(lp), 16, 0, 0)

__device__ __forceinline__ u16 f2bf(float f) {            // RNE fp32->bf16 (no NaN inputs)
    u32 u = __float_as_uint(f);
    return (u16)((u + 0x7FFFu + ((u >> 16) & 1u)) >> 16);
}
__device__ __forceinline__ float bf2f(u16 h) { return __uint_as_float(((u32)h) << 16); }

// dk^-0.5 * log2(e): folded into stored Q so attn uses exp2 directly
#define QSCL 0.12751741859316937f

// ---------------------------------------------------------------------------
// Convert: src fp32 [R][Cc] (batched via z) -> dst_hi/lo bf16 [Cc][R] (transpose+split)
// ---------------------------------------------------------------------------
__global__ __launch_bounds__(256) void conv_split_t(
    const float* __restrict__ src, u16* __restrict__ dhi, u16* __restrict__ dlo,
    int R, int Cc)
{
    __shared__ float Ts[64][65];
    const int tid = threadIdx.x;
    const int c0 = blockIdx.x * 64, r0 = blockIdx.y * 64;
    const size_t bofs = (size_t)blockIdx.z * R * Cc;

#pragma unroll
    for (int p = 0; p < 4; ++p) {
        int r = p * 16 + (tid >> 4);
        int c = (tid & 15) * 4;
        float4 v = *(const float4*)(src + bofs + (size_t)(r0 + r) * Cc + c0 + c);
        Ts[c + 0][r] = v.x; Ts[c + 1][r] = v.y; Ts[c + 2][r] = v.z; Ts[c + 3][r] = v.w;
    }
    __syncthreads();
#pragma unroll
    for (int p = 0; p < 4; ++p) {
        int cc = p * 16 + (tid >> 4);
        int rr = (tid & 15) * 4;
        float f0 = Ts[cc][rr + 0], f1 = Ts[cc][rr + 1];
        float f2 = Ts[cc][rr + 2], f3 = Ts[cc][rr + 3];
        u16 h0 = f2bf(f0), h1 = f2bf(f1), h2 = f2bf(f2), h3 = f2bf(f3);
        u16 l0 = f2bf(f0 - bf2f(h0)), l1 = f2bf(f1 - bf2f(h1));
        u16 l2 = f2bf(f2 - bf2f(h2)), l3 = f2bf(f3 - bf2f(h3));
        size_t o = bofs + (size_t)(c0 + cc) * R + r0 + rr;
        *(uint2*)(void*)(dhi + o) = make_uint2((u32)h0 | ((u32)h1 << 16), (u32)h2 | ((u32)h3 << 16));
        *(uint2*)(void*)(dlo + o) = make_uint2((u32)l0 | ((u32)l1 << 16), (u32)l2 | ((u32)l3 << 16));
    }
}

// ---------------------------------------------------------------------------
// QKV projection, split-bf16 MFMA (round-8 proven epilogue: scattered stores).
//   Q hi/lo [b][h][n][d] (prescaled), K hi/lo [b][h][n][d], Vt hi/lo [b][h][d][n]
// ---------------------------------------------------------------------------
__global__ __launch_bounds__(256, 2) void qkv_mfma(
    const u16* __restrict__ xt_hi, const u16* __restrict__ xt_lo,
    const u16* __restrict__ wpT_hi, const u16* __restrict__ wpT_lo,
    const float* __restrict__ bp,
    u16* __restrict__ Qh, u16* __restrict__ Ql,
    u16* __restrict__ Kh, u16* __restrict__ Kl,
    u16* __restrict__ Vth, u16* __restrict__ Vtl)
{
    __shared__ __align__(16) u16 AH[128 * 64], AL[128 * 64], BH[128 * 64], BL[128 * 64];
    const int tid = threadIdx.x;
    const int l = tid & 63, w = tid >> 6;
    const int wr = w >> 1, wc = w & 1;
    const int lm = l & 15, kg = l >> 4;
    const int bx = blockIdx.x, by = blockIdx.y, b = blockIdx.z;
    const int m0 = bx * 128, n0 = by * 128;

    const u16* gsrc =
        (w == 0) ? xt_hi + ((size_t)b * N_ + n0) * C_ :
        (w == 1) ? xt_lo + ((size_t)b * N_ + n0) * C_ :
        (w == 2) ? wpT_hi + (size_t)m0 * C_ :
                   wpT_lo + (size_t)m0 * C_;
    u16* ldst = (w == 0) ? AH : (w == 1) ? AL : (w == 2) ? BH : BL;
    const int lane_off = (l >> 3) * C_ + (((l & 7) ^ (l >> 3)) << 3);

    f4 acc[4][4] = {};

    for (int it = 0; it < 8; ++it) {
        __syncthreads();
        const u16* g = gsrc + it * 64 + lane_off;
#pragma unroll
        for (int u = 0; u < 16; ++u)
            GL2LDS(g + (size_t)u * 8 * C_, ldst + u * 512);
        __syncthreads();

#pragma unroll
        for (int kk = 0; kk < 2; ++kk) {
            bfrag ah[4], al[4], bh[4], bl[4];
            const int s = ((kk * 4 + kg) ^ (lm & 7)) << 3;
#pragma unroll
            for (int f = 0; f < 4; ++f) {
                const int ar = wr * 64 + f * 16 + lm;
                const int br = wc * 64 + f * 16 + lm;
                ah[f] = *(const bfrag*)(AH + ar * 64 + s);
                al[f] = *(const bfrag*)(AL + ar * 64 + s);
                bh[f] = *(const bfrag*)(BH + br * 64 + s);
                bl[f] = *(const bfrag*)(BL + br * 64 + s);
            }
#pragma unroll
            for (int i = 0; i < 4; ++i)
#pragma unroll
                for (int j = 0; j < 4; ++j) {
                    acc[i][j] = MFMA(ah[i], bh[j], acc[i][j]);
                    acc[i][j] = MFMA(ah[i], bl[j], acc[i][j]);
                    acc[i][j] = MFMA(al[i], bh[j], acc[i][j]);
                }
        }
    }

    const int hh = bx / 3, t = bx - hh * 3;
#pragma unroll
    for (int j = 0; j < 4; ++j) {
        const int mcol = m0 + wc * 64 + j * 16 + lm;
        const float bias = bp[mcol];
        const int d = mcol & 127;
#pragma unroll
        for (int i = 0; i < 4; ++i) {
            const int tok = n0 + wr * 64 + i * 16 + kg * 4;
            if (t == 2) {
                u16 hb[4], lb[4];
#pragma unroll
                for (int r = 0; r < 4; ++r) {
                    float v = acc[i][j][r] + bias;
                    hb[r] = f2bf(v);
                    lb[r] = f2bf(v - bf2f(hb[r]));
                }
                const size_t o = ((size_t)(b * NH + hh) * DK + d) * N_ + tok;
                *(uint2*)(void*)(Vth + o) = make_uint2((u32)hb[0] | ((u32)hb[1] << 16),
                                                       (u32)hb[2] | ((u32)hb[3] << 16));
                *(uint2*)(void*)(Vtl + o) = make_uint2((u32)lb[0] | ((u32)lb[1] << 16),
                                                       (u32)lb[2] | ((u32)lb[3] << 16));
            } else {
                u16* dh = (t == 0) ? Qh : Kh;
                u16* dl = (t == 0) ? Ql : Kl;
                const size_t o = ((size_t)(b * NH + hh) * N_ + tok) * DK + d;
#pragma unroll
                for (int r = 0; r < 4; ++r) {
                    float v = acc[i][j][r] + bias;
                    if (t == 0) v *= QSCL;
                    u16 hb = f2bf(v);
                    dh[o + (size_t)r * DK] = hb;
                    dl[o + (size_t)r * DK] = f2bf(v - bf2f(hb));
                }
            }
        }
    }
}

// ---------------------------------------------------------------------------
// Flash attention, split-bf16 MFMA, swapped operands (S^T = K·Q^T).
// 256 threads = 4 waves, 2 q-sets/wave, KVBLK=32, 2 blocks/CU.
// Round-10 edits: T5 setprio around MFMA clusters (2 blocks/CU = phase
// diversity, m191 +4-7%); T13 skip-rescale when __all(mt<=m_r) (bit-exact:
// skipped multiply is by 1.0); P-hi via truncation (split pair still exact).
// ---------------------------------------------------------------------------
__global__ __launch_bounds__(256, 2) void attn_mfma(
    const u16* __restrict__ Qh_, const u16* __restrict__ Ql_,
    const u16* __restrict__ Kh_, const u16* __restrict__ Kl_,
    const u16* __restrict__ Vth_, const u16* __restrict__ Vtl_,
    u16* __restrict__ res_hi, u16* __restrict__ res_lo)
{
    __shared__ __align__(16) u16 KH[32 * 128], KL[32 * 128];   // [j][d], chunk-swizzled
    __shared__ __align__(16) u16 VH[128 * 32], VL[128 * 32];   // [d][n], chunk-swizzled
    __shared__ u16 Ph[4][2][16][40], Pl[4][2][16][40];         // per-wave, per-set

    const int tid = threadIdx.x;
    const int l = tid & 63, w = tid >> 6;     // 4 waves
    const int lm = l & 15, kg = l >> 4;
    const int bh = blockIdx.x;                // 0..63 (b*NH+h)
    const int qc = blockIdx.y;                // 0..7
    const int i0s = qc * 128 + w * 16 + lm;   // set0 q-row; set1 = +64
    const size_t head = (size_t)bh * N_ * DK;

    // Q fragments (B-operand), both sets
    bfrag qfh[2][4], qfl[2][4];
#pragma unroll
    for (int s = 0; s < 2; ++s) {
        const u16* qp  = Qh_ + head + (size_t)(i0s + s * 64) * DK + kg * 8;
        const u16* qp2 = Ql_ + head + (size_t)(i0s + s * 64) * DK + kg * 8;
#pragma unroll
        for (int kc = 0; kc < 4; ++kc) {
            qfh[s][kc] = *(const bfrag*)(qp + kc * 32);
            qfl[s][kc] = *(const bfrag*)(qp2 + kc * 32);
        }
    }

    f4 acc_o[2][8] = {};
    float m_r[2] = {-3.0e38f, -3.0e38f}, l_r[2] = {0.f, 0.f};

    for (int jt = 0; jt < 32; ++jt) {
        __syncthreads();   // prior iteration's K/V LDS reads complete
        if (w < 2) {
            const u16* sg = (w & 1) ? Kl_ : Kh_;
            u16* sd = (w & 1) ? KL : KH;
#pragma unroll
            for (int u = 0; u < 8; ++u) {
                const int rbase = u * 4;
                const int row = rbase + (l >> 4);
                GL2LDS(sg + head + (size_t)(jt * 32 + row) * DK + (((l & 15) ^ (row & 7)) << 3),
                       sd + rbase * 128);
            }
        } else {
            const u16* sg = (w & 1) ? Vtl_ : Vth_;
            u16* sd = (w & 1) ? VL : VH;
#pragma unroll
            for (int u = 0; u < 8; ++u) {
                const int rbase = u * 16;
                const int row = rbase + (l >> 2);
                GL2LDS(sg + (size_t)bh * DK * N_ + (size_t)row * N_ + jt * 32
                           + (((l & 3) ^ (row & 3)) << 3),
                       sd + rbase * 32);
            }
        }
        __syncthreads();   // staging landed (vmcnt(0) drained at barrier)

        // ---- S^T = K·Q^T over d=128, both q-sets share each K fragment ----
        f4 sacc[2][2] = {};
        __builtin_amdgcn_s_setprio(1);
#pragma unroll
        for (int kc = 0; kc < 4; ++kc) {
#pragma unroll
            for (int jf = 0; jf < 2; ++jf) {
                const int row = jf * 16 + lm;
                const int sw = (((kc << 2) | kg) ^ (lm & 7)) << 3;
                bfrag kh = *(const bfrag*)(KH + row * 128 + sw);
                bfrag kl = *(const bfrag*)(KL + row * 128 + sw);
#pragma unroll
                for (int s = 0; s < 2; ++s) {
                    sacc[s][jf] = MFMA(kh, qfh[s][kc], sacc[s][jf]);
                    sacc[s][jf] = MFMA(kh, qfl[s][kc], sacc[s][jf]);
                    sacc[s][jf] = MFMA(kl, qfh[s][kc], sacc[s][jf]);
                }
            }
        }
        __builtin_amdgcn_s_setprio(0);

        // ---- online softmax; shfl chains ILP-fused across sets ----
        float mt[2], rs[2];
#pragma unroll
        for (int s = 0; s < 2; ++s) {
            float a = fmaxf(fmaxf(sacc[s][0][0], sacc[s][0][1]),
                            fmaxf(sacc[s][0][2], sacc[s][0][3]));
            float bb = fmaxf(fmaxf(sacc[s][1][0], sacc[s][1][1]),
                             fmaxf(sacc[s][1][2], sacc[s][1][3]));
            mt[s] = fmaxf(a, bb);
        }
        mt[0] = fmaxf(mt[0], __shfl_xor(mt[0], 16));
        mt[1] = fmaxf(mt[1], __shfl_xor(mt[1], 16));
        mt[0] = fmaxf(mt[0], __shfl_xor(mt[0], 32));
        mt[1] = fmaxf(mt[1], __shfl_xor(mt[1], 32));
#pragma unroll
        for (int s = 0; s < 2; ++s) {
            const float mn = fmaxf(m_r[s], mt[s]);
            // T13: when no lane's tile-max exceeds the running max, alpha==1
            // exactly -> the rescale is a multiply by 1.0; skip it (bit-exact).
            if (!__all(mt[s] <= m_r[s])) {
                const float alpha = exp2f(m_r[s] - mn);
                l_r[s] *= alpha;
#pragma unroll
                for (int df = 0; df < 8; ++df)
#pragma unroll
                    for (int r = 0; r < 4; ++r) acc_o[s][df][r] *= alpha;
            }
            m_r[s] = mn;
            rs[s] = 0.f;
#pragma unroll
            for (int jf = 0; jf < 2; ++jf) {
                u16 hb[4], lb[4];
#pragma unroll
                for (int r = 0; r < 4; ++r) {
                    float pv = exp2f(sacc[s][jf][r] - mn);
                    rs[s] += pv;
                    hb[r] = (u16)(__float_as_uint(pv) >> 16);      // trunc split hi
                    lb[r] = f2bf(pv - bf2f(hb[r]));                // exact remainder
                }
                *(uint2*)(void*)&Ph[w][s][lm][jf * 16 + kg * 4] =
                    make_uint2((u32)hb[0] | ((u32)hb[1] << 16), (u32)hb[2] | ((u32)hb[3] << 16));
                *(uint2*)(void*)&Pl[w][s][lm][jf * 16 + kg * 4] =
                    make_uint2((u32)lb[0] | ((u32)lb[1] << 16), (u32)lb[2] | ((u32)lb[3] << 16));
            }
        }
        rs[0] += __shfl_xor(rs[0], 16);
        rs[1] += __shfl_xor(rs[1], 16);
        rs[0] += __shfl_xor(rs[0], 32);
        rs[1] += __shfl_xor(rs[1], 32);
        l_r[0] += rs[0];
        l_r[1] += rs[1];

        // ---- O^T += Vt · P, both P-sets share each V fragment ----
        bfrag pbh0 = *(const bfrag*)&Ph[w][0][lm][kg * 8];
        bfrag pbl0 = *(const bfrag*)&Pl[w][0][lm][kg * 8];
        bfrag pbh1 = *(const bfrag*)&Ph[w][1][lm][kg * 8];
        bfrag pbl1 = *(const bfrag*)&Pl[w][1][lm][kg * 8];
        __builtin_amdgcn_s_setprio(1);
#pragma unroll
        for (int df = 0; df < 8; ++df) {
            const int row = df * 16 + lm;
            const int sw = (kg ^ (lm & 3)) << 3;
            bfrag vh = *(const bfrag*)(VH + row * 32 + sw);
            bfrag vl = *(const bfrag*)(VL + row * 32 + sw);
            acc_o[0][df] = MFMA(vh, pbh0, acc_o[0][df]);
            acc_o[0][df] = MFMA(vh, pbl0, acc_o[0][df]);
            acc_o[0][df] = MFMA(vl, pbh0, acc_o[0][df]);
            acc_o[1][df] = MFMA(vh, pbh1, acc_o[1][df]);
            acc_o[1][df] = MFMA(vh, pbl1, acc_o[1][df]);
            acc_o[1][df] = MFMA(vl, pbh1, acc_o[1][df]);
        }
        __builtin_amdgcn_s_setprio(0);
    }

    // ---- epilogue: res[b][i][h*128+d] = O/l as bf16 hi/lo, both sets ----
    const int b = bh >> 2, h = bh & 3;
#pragma unroll
    for (int s = 0; s < 2; ++s) {
        const float inv = 1.f / l_r[s];
        const size_t ro = ((size_t)b * N_ + i0s + s * 64) * C_ + h * DK;
#pragma unroll
        for (int df = 0; df < 8; ++df) {
            u16 hb[4], lb[4];
#pragma unroll
            for (int r = 0; r < 4; ++r) {
                float v = acc_o[s][df][r] * inv;
                hb[r] = f2bf(v);
                lb[r] = f2bf(v - bf2f(hb[r]));
            }
            const size_t o = ro + df * 16 + kg * 4;
            *(uint2*)(void*)(res_hi + o) = make_uint2((u32)hb[0] | ((u32)hb[1] << 16),
                                                      (u32)hb[2] | ((u32)hb[3] << 16));
            *(uint2*)(void*)(res_lo + o) = make_uint2((u32)lb[0] | ((u32)lb[1] << 16),
                                                      (u32)lb[2] | ((u32)lb[3] << 16));
        }
    }
}

// ---------------------------------------------------------------------------
// Out projection, split-bf16 MFMA, computes outT[c'][n] directly. (+bias +x)
// ---------------------------------------------------------------------------
__global__ __launch_bounds__(256, 2) void out_mfma(
    const u16* __restrict__ woT_hi, const u16* __restrict__ woT_lo,
    const u16* __restrict__ res_hi, const u16* __restrict__ res_lo,
    const float* __restrict__ bo, const float* __restrict__ x,
    float* __restrict__ out)
{
    __shared__ __align__(16) u16 AH[128 * 64], AL[128 * 64], BH[128 * 64], BL[128 * 64];
    const int tid = threadIdx.x;
    const int l = tid & 63, w = tid >> 6;
    const int wr = w >> 1, wc = w & 1;
    const int lm = l & 15, kg = l >> 4;
    const int bx = blockIdx.x, by = blockIdx.y, b = blockIdx.z;
    const int c0 = bx * 128, n0 = by * 128;

    const u16* gsrc =
        (w == 0) ? woT_hi + (size_t)c0 * C_ :
        (w == 1) ? woT_lo + (size_t)c0 * C_ :
        (w == 2) ? res_hi + ((size_t)b * N_ + n0) * C_ :
                   res_lo + ((size_t)b * N_ + n0) * C_;
    u16* ldst = (w == 0) ? AH : (w == 1) ? AL : (w == 2) ? BH : BL;
    const int lane_off = (l >> 3) * C_ + (((l & 7) ^ (l >> 3)) << 3);

    f4 acc[4][4] = {};

    for (int it = 0; it < 8; ++it) {
        __syncthreads();
        const u16* g = gsrc + it * 64 + lane_off;
#pragma unroll
        for (int u = 0; u < 16; ++u)
            GL2LDS(g + (size_t)u * 8 * C_, ldst + u * 512);
        __syncthreads();

#pragma unroll
        for (int kk = 0; kk < 2; ++kk) {
            bfrag ah[4], al[4], bh[4], bl[4];
            const int s = ((kk * 4 + kg) ^ (lm & 7)) << 3;
#pragma unroll
            for (int f = 0; f < 4; ++f) {
                const int ar = wr * 64 + f * 16 + lm;
                const int br = wc * 64 + f * 16 + lm;
                ah[f] = *(const bfrag*)(AH + ar * 64 + s);
                al[f] = *(const bfrag*)(AL + ar * 64 + s);
                bh[f] = *(const bfrag*)(BH + br * 64 + s);
                bl[f] = *(const bfrag*)(BL + br * 64 + s);
            }
#pragma unroll
            for (int i = 0; i < 4; ++i)
#pragma unroll
                for (int j = 0; j < 4; ++j) {
                    acc[i][j] = MFMA(ah[i], bh[j], acc[i][j]);
                    acc[i][j] = MFMA(ah[i], bl[j], acc[i][j]);
                    acc[i][j] = MFMA(al[i], bh[j], acc[i][j]);
                }
        }
    }

#pragma unroll
    for (int j = 0; j < 4; ++j) {
        const int ncol = n0 + wc * 64 + j * 16 + lm;
#pragma unroll
        for (int i = 0; i < 4; ++i) {
#pragma unroll
            for (int r = 0; r < 4; ++r) {
                const int crow = c0 + wr * 64 + i * 16 + kg * 4 + r;
                const size_t o = ((size_t)b * C_ + crow) * N_ + ncol;
                out[o] = acc[i][j][r] + bo[crow] + x[o];
            }
        }
    }
}

extern "C" void kernel_launch(void* const* d_in, const int* in_sizes, int n_in,
                              void* d_out, int out_size, void* d_ws, size_t ws_size,
                              hipStream_t stream) {
    const float* x  = (const float*)d_in[0];
    const float* wp = (const float*)d_in[1];
    const float* bp = (const float*)d_in[2];
    const float* wo = (const float*)d_in[3];
    const float* bo = (const float*)d_in[4];
    float* out = (float*)d_out;

    // ws map (128 MiB). SEG = 8388608 elements.
    //  [0,32M):   xt hi/lo  -> res hi/lo after qkv
    //  [32M,64M): Q hi/lo   (-> woT hi/lo after attn)
    //  [64M,96M): K hi/lo
    //  [96M,128M): Vt hi/lo
    // d_out[0,3M): wpT hi/lo (dead before out_mfma overwrites with output)
    const size_t SEG = (size_t)B_ * N_ * C_;
    u16* xt_hi = (u16*)d_ws;
    u16* xt_lo = xt_hi + SEG;
    u16* Qh  = xt_hi + 2 * SEG;
    u16* Ql  = Qh + SEG;
    u16* Kh  = Ql + SEG;
    u16* Kl  = Kh + SEG;
    u16* Vth = Kl + SEG;
    u16* Vtl = Vth + SEG;
    u16* res_hi = xt_hi;
    u16* res_lo = xt_lo;
    u16* woT_hi = Qh;
    u16* woT_lo = woT_hi + C_ * C_;
    u16* wpT_hi = (u16*)d_out;
    u16* wpT_lo = wpT_hi + C_ * M3;

    conv_split_t<<<dim3(16, 8, 16), 256, 0, stream>>>(x, xt_hi, xt_lo, C_, N_);
    conv_split_t<<<dim3(24, 8, 1), 256, 0, stream>>>(wp, wpT_hi, wpT_lo, C_, M3);
    qkv_mfma<<<dim3(12, 8, 16), 256, 0, stream>>>(xt_hi, xt_lo, wpT_hi, wpT_lo, bp,
                                                  Qh, Ql, Kh, Kl, Vth, Vtl);
    attn_mfma<<<dim3(64, 8), 256, 0, stream>>>(Qh, Ql, Kh, Kl, Vth, Vtl, res_hi, res_lo);
    conv_split_t<<<dim3(8, 8, 1), 256, 0, stream>>>(wo, woT_hi, woT_lo, C_, C_);
    out_mfma<<<dim3(4, 8, 16), 256, 0, stream>>>(woT_hi, woT_lo, res_hi, res_lo, bo, x, out);
}